// Round 14
// baseline (26.273 us; speedup 1.0000x reference)
//
#include <hip/hip_runtime.h>
#include <math.h>

#define DIM 1024
#define KK 7
#define DIL 2
#define BATCH 16384
#define NEG 0.01f
#define ROWS 8      // rows per block, grid = 2048 (= 8 blocks/CU exactly, no tail)
#define NBUF 3      // per-wave row slots (depth-2 prefetch + current)
#define DEPTH 2     // rows issued ahead
#define SLOT 320    // floats per slot: 256 main + halo region (windows read [0,268))

typedef float f32x2 __attribute__((ext_vector_type(2)));

// Direct global->LDS DMA; no destination VGPR -> un-sinkable; vmcnt-tracked.
__device__ __forceinline__ void gload_lds16(const float* g, float* l) {
    __builtin_amdgcn_global_load_lds(
        (const __attribute__((address_space(1))) void*)g,
        (__attribute__((address_space(3))) void*)l, 16, 0, 0);
}
__device__ __forceinline__ void gload_lds4(const float* g, float* l) {
    __builtin_amdgcn_global_load_lds(
        (const __attribute__((address_space(1))) void*)g,
        (__attribute__((address_space(3))) void*)l, 4, 0, 0);
}

// ---------------------------------------------------------------------------
// R13 structure (barrier-free per-wave pipelines, counted vmcnt {4,5,6,6,6,6,
// 4,2}, clamped halo) with ONE change: the hot-loop arithmetic is packed into
// f32x2 ops targeting v_pk_fma_f32 (VOP3P). The dilation-2 conv is exactly
// pair-packable: features (0,1) tap (xv[2k],xv[2k+1]) = xw[k] with broadcast
// w[k]; features (2,3) tap xw[k+1]. 28 scalar FMA -> 14 pk FMA; NEG-mul and
// scale/skip fma also pack. ~30% hot-VALU cut, memory ops byte-identical.
// ---------------------------------------------------------------------------
__global__ __launch_bounds__(256)
void cnn_flow_fused(const float* __restrict__ x,
                    const float* __restrict__ wgt,
                    const float* __restrict__ bias,
                    const float* __restrict__ lmbd,
                    float* __restrict__ out,
                    float* __restrict__ logdet) {
    const int t    = threadIdx.x;
    const int wv   = t >> 6;
    const int lane = t & 63;
    const int base = t << 2;                  // global feature = wv*256+lane*4
    const int row0 = blockIdx.x * ROWS;

    __shared__ float sx[4 * NBUF * SLOT];     // 15360 B staging
    __shared__ float red[ROWS][4];            // per-row wave partials
    __shared__ float dummy[64];               // sink for wave 3's halo loads

    // wave 3: zero the read-halo region of its own slots once (never gloaded)
    if (wv == 3 && lane < 16) {
#pragma unroll
        for (int s = 0; s < NBUF; ++s)
            sx[(3 * NBUF + s) * SLOT + 256 + lane] = 0.0f;
    }

    const float* growbase = x + (size_t)row0 * DIM;
    const float* gmain = growbase + (wv << 8) + (lane << 2);   // 16B/lane
    // halo: lanes >=12 clamp to float 11 -> same 64B line, full exec mask
    const int hl = (lane < 12) ? lane : 11;
    const float* ghalo = growbase + ((wv < 3) ? (wv << 8) + 256 : 0) + hl;

    auto issue_row = [&](int r) {
        float* slot = sx + (wv * NBUF + (r % NBUF)) * SLOT;
        gload_lds16(gmain + r * DIM, slot + (lane << 2));
        gload_lds4(ghalo + r * DIM, ((wv < 3) ? slot + 256 : dummy) + lane);
    };

    // prologue: rows 0,1 in flight
    issue_row(0);
    issue_row(1);

    // scalar params + per-feature tables: computed while prologue loads fly
    float w[KK];
#pragma unroll
    for (int k = 0; k < KK; ++k) w[k] = wgt[k];
    const float w0 = w[0];
    const float bs = bias[0];

    f32x2 w2[KK];                              // broadcast weight pairs
#pragma unroll
    for (int k = 0; k < KK; ++k) { w2[k].x = w[k]; w2[k].y = w[k]; }

    float sc[4], lp[4], ln[4];
    {
        float4 lm = *reinterpret_cast<const float4*>(lmbd + base);
        float lms[4] = {lm.x, lm.y, lm.z, lm.w};
        const float inv = (w0 != 0.0f) ? (-1.0f / w0) : 0.0f;
#pragma unroll
        for (int i = 0; i < 4; ++i) {
            float l  = lms[i];
            float sp = fmaxf(l, 0.0f) + log1pf(expf(-fabsf(l)));  // softplus
            float scale;
            if (w0 == 0.0f)      scale = l;
            else if (w0 > 0.0f)  scale = inv + sp;
            else                 scale = inv - sp;
            sc[i] = scale;
            lp[i] = logf(fabsf(fmaf(scale,       w0, 1.0f)));   // act_grad=1
            ln[i] = logf(fabsf(fmaf(NEG * scale, w0, 1.0f)));   // act_grad=NEG
        }
    }
    f32x2 sc01; sc01.x = sc[0]; sc01.y = sc[1];
    f32x2 sc23; sc23.x = sc[2]; sc23.y = sc[3];
    const f32x2 vneg = {NEG, NEG};

#pragma unroll
    for (int r = 0; r < ROWS; ++r) {
        if (r + DEPTH < ROWS) issue_row(r + DEPTH);

        // counted per-wave wait: row r's 2 load instrs retired, newer loads +
        // stores stay in flight. Position-derived: {4,5,6,6,6,6,4,2}.
        if      (r == 0) asm volatile("s_waitcnt vmcnt(4)" ::: "memory");
        else if (r == 1) asm volatile("s_waitcnt vmcnt(5)" ::: "memory");
        else if (r == 6) asm volatile("s_waitcnt vmcnt(4)" ::: "memory");
        else if (r == 7) asm volatile("s_waitcnt vmcnt(2)" ::: "memory");
        else             asm volatile("s_waitcnt vmcnt(6)" ::: "memory");

        const float* srow = sx + (wv * NBUF + (r % NBUF)) * SLOT + (lane << 2);
        float xv[16];
#pragma unroll
        for (int j = 0; j < 4; ++j) {         // 4x ds_read_b128, wave-private
            float4 v = *reinterpret_cast<const float4*>(srow + 4 * j);
            xv[4 * j + 0] = v.x; xv[4 * j + 1] = v.y;
            xv[4 * j + 2] = v.z; xv[4 * j + 3] = v.w;
        }
        f32x2 xw[8];
#pragma unroll
        for (int j = 0; j < 8; ++j) { xw[j].x = xv[2 * j]; xw[j].y = xv[2 * j + 1]; }

        // packed conv: pair (0,1) taps xw[k], pair (2,3) taps xw[k+1]
        f32x2 c01 = {bs, bs}, c23 = {bs, bs};
#pragma unroll
        for (int k = 0; k < KK; ++k) {
            c01 = __builtin_elementwise_fma(xw[k],     w2[k], c01);
            c23 = __builtin_elementwise_fma(xw[k + 1], w2[k], c23);
        }

        // packed leaky-relu + scale + skip
        f32x2 n01 = c01 * vneg, n23 = c23 * vneg;
        bool p0 = c01.x >= 0.0f, p1 = c01.y >= 0.0f;
        bool p2 = c23.x >= 0.0f, p3 = c23.y >= 0.0f;
        f32x2 a01; a01.x = p0 ? c01.x : n01.x; a01.y = p1 ? c01.y : n01.y;
        f32x2 a23; a23.x = p2 ? c23.x : n23.x; a23.y = p3 ? c23.y : n23.y;
        f32x2 o01 = __builtin_elementwise_fma(a01, sc01, xw[0]);
        f32x2 o23 = __builtin_elementwise_fma(a23, sc23, xw[1]);

        *reinterpret_cast<float4*>(out + (size_t)(row0 + r) * DIM + base) =
            make_float4(o01.x, o01.y, o23.x, o23.y);

        float ld_acc = (p0 ? lp[0] : ln[0]) + (p1 ? lp[1] : ln[1])
                     + (p2 ? lp[2] : ln[2]) + (p3 ? lp[3] : ln[3]);

        // wave shuffle reduce (hidden); park per-wave partial, fire-and-forget
#pragma unroll
        for (int off = 32; off > 0; off >>= 1)
            ld_acc += __shfl_down(ld_acc, off, 64);
        if (lane == 0) red[r][wv] = ld_acc;
    }

    __syncthreads();                          // only barrier in the kernel
    if (t < ROWS)
        logdet[row0 + t] = (red[t][0] + red[t][1]) + (red[t][2] + red[t][3]);
}

extern "C" void kernel_launch(void* const* d_in, const int* in_sizes, int n_in,
                              void* d_out, int out_size, void* d_ws, size_t ws_size,
                              hipStream_t stream) {
    const float* x    = (const float*)d_in[0];
    const float* wgt  = (const float*)d_in[1];
    const float* bias = (const float*)d_in[2];
    const float* lmbd = (const float*)d_in[3];
    float* out    = (float*)d_out;                    // (BATCH, DIM)
    float* logdet = out + (size_t)BATCH * DIM;        // (BATCH,)

    cnn_flow_fused<<<BATCH / ROWS, 256, 0, stream>>>(x, wgt, bias, lmbd, out, logdet);
}